// Round 17
// baseline (487.034 us; speedup 1.0000x reference)
//
#include <hip/hip_runtime.h>
#include <math.h>

#define NN 100000
#define EE 800000
#define CC 47
#define HH 128
#define NB 391      // node buckets of 256
#define CHUNK 2000  // edges per coarse block
#define CH (CC * HH)
#define PACKN (5 * 16384 + 6144)
#define PBN (3125 * 2048)   // p packed in A-frag order

typedef __attribute__((ext_vector_type(8))) short short8v;
typedef __attribute__((ext_vector_type(4))) float float4v;

__device__ inline ushort f2bf(float f) {
    unsigned u = __float_as_uint(f);
    unsigned r = (u + 0x7fffu + ((u >> 16) & 1u)) >> 16;  // RNE
    return (ushort)r;
}
__device__ inline float b2f(ushort u) { return __uint_as_float(((unsigned)u) << 16); }

// ---------------- prep: zero accumulators + pack all weights (one launch) ----------------
__global__ __launch_bounds__(256) void prep_kernel(const float* __restrict__ lin0_w,
                                                   const float* __restrict__ conv_w,
                                                   const float* __restrict__ W1,
                                                   ushort* __restrict__ wp0,
                                                   ushort* __restrict__ wpc,
                                                   ushort* __restrict__ wp1,
                                                   int* __restrict__ z, int ztot) {
    int idx = blockIdx.x * 256 + threadIdx.x;
    int stride = gridDim.x * 256;
    for (int i = idx; i < ztot; i += stride) z[i] = 0;
    for (int i = idx; i < PACKN; i += stride) {
        if (i < 5 * 16384) {
            int m = i >> 14;
            int r = i & 16383;
            int k = r >> 7, c = r & 127;
            const float* W = (m == 0) ? lin0_w : conv_w + (size_t)(m - 1) * 16384;
            ushort* Wp = (m == 0) ? wp0 : wpc + (size_t)(m - 1) * 16384;
            Wp[(k >> 3) * 1024 + c * 8 + (k & 7)] = f2bf(W[r]);
        } else {
            int j = i - 5 * 16384;
            int ksub = j / 384, rem = j - ksub * 384;
            int c = rem >> 3, kk = ksub * 8 + (rem & 7);
            wp1[j] = (c < CC) ? f2bf(W1[kk * CC + c]) : (ushort)0;
        }
    }
}

// ---------------- pack p [N][47] f32 -> per-tile MFMA A-fragment order bf16 ----------------
// pb[t*2048 + (ks*4+sub)*256 + half*128 + r16*8 + j] = bf16(p[(t*32+half*16+r16)*47 + ks*32+sub*8+j])
__global__ __launch_bounds__(256) void pack_p_kernel(const float* __restrict__ p,
                                                     ushort* __restrict__ pb) {
    int idx = blockIdx.x * 256 + threadIdx.x;
    if (idx >= PBN) return;
    int t = idx >> 11;
    int rem = idx & 2047;
    int grp = rem >> 8;          // ks*4+sub
    int rem2 = rem & 255;
    int half = rem2 >> 7;
    int r16 = (rem2 >> 3) & 15;
    int j = rem2 & 7;
    int row = t * 32 + half * 16 + r16;
    int k = (grp >> 2) * 32 + (grp & 3) * 8 + j;
    pb[idx] = (k < CC) ? f2bf(p[(size_t)row * CC + k]) : (ushort)0;
}

// ---------------- fused histograms: edge-degree + label counts ----------------
__global__ __launch_bounds__(256) void hist2_kernel(const int* __restrict__ dst,
                                                    int* __restrict__ deg,
                                                    const int* __restrict__ label,
                                                    int* __restrict__ lcnt, int e, int n) {
    __shared__ int lh[CC];
    int t = threadIdx.x;
    if (t < CC) lh[t] = 0;
    __syncthreads();
    int i = blockIdx.x * 256 + t;
    if (i < e) atomicAdd(&deg[dst[i]], 1);
    bool has = blockIdx.x < (unsigned)((n + 255) / 256);
    if (has && i < n) atomicAdd(&lh[label[i]], 1);
    __syncthreads();
    if (has && t < CC && lh[t] > 0) atomicAdd(&lcnt[t], lh[t]);
}

__global__ __launch_bounds__(256) void scan_block_kernel(const int* __restrict__ deg,
                                                         int* __restrict__ rowptr,
                                                         int* __restrict__ bsum, int n) {
    __shared__ int ls[256];
    int b = blockIdx.x, t = threadIdx.x;
    int i0 = b * 512 + 2 * t;
    int a0 = (i0 < n) ? deg[i0] : 0;
    int a1 = (i0 + 1 < n) ? deg[i0 + 1] : 0;
    int val = a0 + a1;
    ls[t] = val;
    __syncthreads();
    for (int off = 1; off < 256; off <<= 1) {
        int add = (t >= off) ? ls[t - off] : 0;
        __syncthreads();
        val += add;
        ls[t] = val;
        __syncthreads();
    }
    int incl1 = val;
    int incl0 = val - a1;
    if (i0 < n) rowptr[i0 + 1] = incl0;
    if (i0 + 1 < n) rowptr[i0 + 2] = incl1;
    if (t == 255) bsum[b] = val;
}

// block 0: exclusive block-offset scan of bsum; block 1: label scan + cnt float copy
__global__ __launch_bounds__(256) void scan2_kernel(int* __restrict__ bsum, int nb,
                                                    const int* __restrict__ lcnt,
                                                    int* __restrict__ lbase,
                                                    int* __restrict__ gcur,
                                                    float* __restrict__ cntf) {
    if (blockIdx.x == 0) {
        __shared__ int ls[256];
        int t = threadIdx.x;
        int v = (t < nb) ? bsum[t] : 0;
        int orig = v;
        ls[t] = v;
        __syncthreads();
        for (int off = 1; off < 256; off <<= 1) {
            int add = (t >= off) ? ls[t - off] : 0;
            __syncthreads();
            v += add;
            ls[t] = v;
            __syncthreads();
        }
        if (t < nb) bsum[t] = v - orig;
    } else {
        __shared__ int ls[CC];
        int t = threadIdx.x;
        if (t < CC) {
            int v = lcnt[t];
            cntf[t] = (float)v;
            gcur[t] = 0;
            ls[t] = v;
        }
        __syncthreads();
        if (t == 0) {
            int run = 0;
            for (int c = 0; c < CC; c++) { int x = ls[c]; ls[c] = run; run += x; }
        }
        __syncthreads();
        if (t < CC) lbase[t] = ls[t];
    }
}

// add block offsets to rowptr AND compute bucket cursors analytically (race-free)
__global__ __launch_bounds__(256) void addoff_init_kernel(int* __restrict__ rowptr,
                                                          const int* __restrict__ bsum,
                                                          int* __restrict__ bcur, int n) {
    int i = blockIdx.x * 256 + threadIdx.x;
    if (i < n) {
        int v = rowptr[i + 1] + bsum[i >> 9];
        rowptr[i + 1] = v;
        if (((i + 1) & 255) == 0 && ((i + 1) >> 8) < 512) bcur[(i + 1) >> 8] = v;
    }
    if (i == 0) { rowptr[0] = 0; bcur[0] = 0; }
    if (i < 512 && i * 256 >= n) bcur[i] = EE;
}

// ---------------- binned CSR fill ----------------
__global__ __launch_bounds__(256) void coarse_fill_kernel(const int* __restrict__ src,
                                                          const int* __restrict__ dst,
                                                          const float* __restrict__ ew,
                                                          int* __restrict__ bcur,
                                                          int2* __restrict__ stage, int e) {
    __shared__ int hist[512];
    __shared__ int base_local[512];
    __shared__ int gbase[512];
    __shared__ int lc[512];
    __shared__ int ls[256];
    __shared__ int2 le[CHUNK];
    __shared__ ushort lb[CHUNK];
    int t = threadIdx.x;
    int beg = blockIdx.x * CHUNK, end = min(e, beg + CHUNK);
    int cnt = end - beg;
    for (int i = t; i < 512; i += 256) { hist[i] = 0; lc[i] = 0; }
    __syncthreads();
    for (int i = beg + t; i < end; i += 256) atomicAdd(&hist[((unsigned)dst[i]) >> 8], 1);
    __syncthreads();
    int a0 = hist[2 * t], a1 = hist[2 * t + 1];
    int val = a0 + a1;
    ls[t] = val;
    __syncthreads();
    for (int off = 1; off < 256; off <<= 1) {
        int add = (t >= off) ? ls[t - off] : 0;
        __syncthreads();
        val += add;
        ls[t] = val;
        __syncthreads();
    }
    base_local[2 * t] = val - a0 - a1;
    base_local[2 * t + 1] = val - a1;
    __syncthreads();
    for (int b = t; b < 512; b += 256)
        if (hist[b] > 0) gbase[b] = atomicAdd(&bcur[b], hist[b]);
    __syncthreads();
    for (int i = beg + t; i < end; i += 256) {
        int d = dst[i];
        int bk = ((unsigned)d) >> 8;
        int slot = base_local[bk] + atomicAdd(&lc[bk], 1);
        le[slot] = make_int2(((d & 255) << 24) | src[i], __float_as_int(ew[i]));
        lb[slot] = (ushort)bk;
    }
    __syncthreads();
    for (int s = t; s < cnt; s += 256) {
        int bk = lb[s];
        stage[gbase[bk] + (s - base_local[bk])] = le[s];
    }
}

__global__ __launch_bounds__(256) void fine_fill_kernel(const int2* __restrict__ stage,
                                                        const int* __restrict__ rowptr,
                                                        int2* __restrict__ csr, int n) {
    __shared__ int cur[256];
    __shared__ int rp[257];
    int b = blockIdx.x, t = threadIdx.x;
    int node0 = b * 256;
    int nodes = min(256, n - node0);
    cur[t] = 0;
    rp[t] = rowptr[min(node0 + t, n)];
    if (t == 0) rp[256] = rowptr[min(node0 + 256, n)];
    __syncthreads();
    int S = rp[0], E = rp[nodes];
    for (int i = S + t; i < E; i += 256) {
        int2 en = stage[i];
        int dl = ((unsigned)en.x) >> 24;
        int pos = rp[dl] + atomicAdd(&cur[dl], 1);
        csr[pos] = make_int2(en.x & 0xFFFFFF, en.y);
    }
}

__global__ __launch_bounds__(256) void lfill_kernel(const int* __restrict__ label,
                                                    const int* __restrict__ lbase,
                                                    int* __restrict__ gcur,
                                                    int* __restrict__ perm, int n) {
    __shared__ int lh[CC], lbs[CC], lc[CC];
    int t = threadIdx.x;
    if (t < CC) lh[t] = 0;
    __syncthreads();
    int chunk = (n + gridDim.x - 1) / gridDim.x;
    int beg = blockIdx.x * chunk, end = min(n, beg + chunk);
    for (int i = beg + t; i < end; i += 256) atomicAdd(&lh[label[i]], 1);
    __syncthreads();
    if (t < CC) {
        lbs[t] = (lh[t] > 0) ? atomicAdd(&gcur[t], lh[t]) : 0;
        lc[t] = 0;
    }
    __syncthreads();
    for (int i = beg + t; i < end; i += 256) {
        int c = label[i];
        int pos = atomicAdd(&lc[c], 1);
        perm[lbase[c] + lbs[c] + pos] = (c << 24) | i;
    }
}

// ---------------- segment sums via sorted perm (8-deep batches, 16 nodes/wave) ----------------
__global__ __launch_bounds__(256) void psum_kernel(const ushort* __restrict__ xb,
                                                   const int* __restrict__ perm,
                                                   float* __restrict__ sums, int n) {
    const int lane = threadIdx.x & 63;
    const int wid = threadIdx.x >> 6;
    int gw = blockIdx.x * 4 + wid;
    int nw = gridDim.x * 4;
    int per = (n + nw - 1) / nw;
    int beg = gw * per, end = min(n, beg + per);
    if (beg >= end) return;
    float ax = 0.0f, ay = 0.0f;
    int ccur = __builtin_amdgcn_readfirstlane(perm[beg]) >> 24;
    int i = beg;
    while (i < end) {
        if (i + 8 <= end) {
            int pp[8];
            #pragma unroll
            for (int u = 0; u < 8; u++) pp[u] = __builtin_amdgcn_readfirstlane(perm[i + u]);
            if ((pp[0] >> 24) == (pp[7] >> 24)) {
                int c = pp[0] >> 24;
                if (c != ccur) {
                    atomicAdd(&sums[ccur * HH + 2 * lane], ax);
                    atomicAdd(&sums[ccur * HH + 2 * lane + 1], ay);
                    ax = ay = 0.0f;
                    ccur = c;
                }
                ushort2 vv[8];
                #pragma unroll
                for (int u = 0; u < 8; u++)
                    vv[u] = *(const ushort2*)(xb + (size_t)(pp[u] & 0xFFFFFF) * HH + 2 * lane);
                #pragma unroll
                for (int u = 0; u < 8; u++) {
                    ax += b2f(vv[u].x);
                    ay += b2f(vv[u].y);
                }
                i += 8;
                continue;
            }
        }
        int pe = __builtin_amdgcn_readfirstlane(perm[i]);
        int c = pe >> 24;
        if (c != ccur) {
            atomicAdd(&sums[ccur * HH + 2 * lane], ax);
            atomicAdd(&sums[ccur * HH + 2 * lane + 1], ay);
            ax = ay = 0.0f;
            ccur = c;
        }
        ushort2 v = *(const ushort2*)(xb + (size_t)(pe & 0xFFFFFF) * HH + 2 * lane);
        ax += b2f(v.x);
        ay += b2f(v.y);
        i += 1;
    }
    atomicAdd(&sums[ccur * HH + 2 * lane], ax);
    atomicAdd(&sums[ccur * HH + 2 * lane + 1], ay);
}

// ---------------- lin0 (B-frags from L2) ----------------
__global__ __launch_bounds__(256) void lin0_mfma_kernel(const float* __restrict__ xin,
                                                        const ushort* __restrict__ Wp,
                                                        const float* __restrict__ bias,
                                                        ushort* __restrict__ x0b,
                                                        ushort* __restrict__ xb) {
    __shared__ ushort ts[32 * 128];
    const int lane = threadIdx.x & 63, wv = threadIdx.x >> 6;
    const int sub = lane >> 4, r16 = lane & 15;
    const int wbase = wv * 32;
    const int rowbase = blockIdx.x * 32;
    const float* tp = xin + (size_t)rowbase * HH;
    #pragma unroll
    for (int j = 0; j < 4; j++) {
        int e = 4 * threadIdx.x + j * 1024;
        float4 f = *(const float4*)(tp + e);
        int r = e >> 7, c = e & 127;
        ushort4 b4 = make_ushort4(f2bf(f.x), f2bf(f.y), f2bf(f.z), f2bf(f.w));
        int off = (r * 256 + c * 2) ^ ((r & 7) << 4);
        *(ushort4*)((char*)ts + off) = b4;
    }
    __syncthreads();
    float4v acc[2][2] = {};
    {
        const char* tsc = (const char*)ts;
        const int sw = (r16 & 7) << 4;
        #pragma unroll
        for (int ks = 0; ks < 4; ks++) {
            short8v a0 = *(const short8v*)(tsc + ((r16 * 256 + ks * 64 + sub * 16) ^ sw));
            short8v a1 = *(const short8v*)(tsc + (((16 + r16) * 256 + ks * 64 + sub * 16) ^ sw));
            int kb = (ks * 4 + sub) * 1024;
            short8v b0 = *(const short8v*)(Wp + kb + (wbase + r16) * 8);
            short8v b1 = *(const short8v*)(Wp + kb + (wbase + 16 + r16) * 8);
            acc[0][0] = __builtin_amdgcn_mfma_f32_16x16x32_bf16(a0, b0, acc[0][0], 0, 0, 0);
            acc[0][1] = __builtin_amdgcn_mfma_f32_16x16x32_bf16(a0, b1, acc[0][1], 0, 0, 0);
            acc[1][0] = __builtin_amdgcn_mfma_f32_16x16x32_bf16(a1, b0, acc[1][0], 0, 0, 0);
            acc[1][1] = __builtin_amdgcn_mfma_f32_16x16x32_bf16(a1, b1, acc[1][1], 0, 0, 0);
        }
    }
    float bv[2] = {bias[wbase + r16], bias[wbase + 16 + r16]};
    #pragma unroll
    for (int mi = 0; mi < 2; mi++)
        #pragma unroll
        for (int ni = 0; ni < 2; ni++) {
            int col = wbase + ni * 16 + r16;
            #pragma unroll
            for (int r = 0; r < 4; r++) {
                int row = rowbase + mi * 16 + sub * 4 + r;
                float v = fmaxf(acc[mi][ni][r] + bv[ni], 0.0f);
                ushort bv16 = f2bf(v);
                x0b[(size_t)row * HH + col] = bv16;
                xb[(size_t)row * HH + col] = bv16;
            }
        }
}

// ---------------- fused centers + rcm + pack ----------------
__global__ __launch_bounds__(64) void cr_kernel(const float* __restrict__ sumsx,
                                                const float* __restrict__ sums0,
                                                const float* __restrict__ cnt,
                                                const float* __restrict__ cm,
                                                ushort* __restrict__ rlp) {
    __shared__ float cs[CC * HH];
    int i = blockIdx.x, lane = threadIdx.x;
    for (int idx = lane; idx < CC * HH; idx += 64) {
        int c = idx >> 7;
        cs[idx] = (sumsx[idx] + 0.1f * sums0[idx]) / fmaxf(cnt[c], 1.0f);
    }
    __syncthreads();
    float ci0 = cs[i * HH + lane];
    float ci1 = cs[i * HH + 64 + lane];
    float acc0 = 0.0f, acc1 = 0.0f;
    for (int j = 0; j < CC; j++) {
        float d0 = ci0 - cs[j * HH + lane];
        float d1 = ci1 - cs[j * HH + 64 + lane];
        float s = d0 * d0 + d1 * d1;
        #pragma unroll
        for (int off = 32; off >= 1; off >>= 1) s += __shfl_xor(s, off);
        float nrm = sqrtf(s);
        if (nrm == 0.0f) nrm = 1.0f;
        float w = cm[i * CC + j] / nrm;
        acc0 = fmaf(w, d0, acc0);
        acc1 = fmaf(w, d1, acc1);
    }
    rlp[(i >> 3) * 1024 + lane * 8 + (i & 7)] = f2bf(acc0);
    rlp[(i >> 3) * 1024 + (lane + 64) * 8 + (i & 7)] = f2bf(acc1);
}

// ---------------- fused layer: pr MFMA (A from packed global) + gather/combine + conv MFMA ----------------
template <int FINAL>
__global__ __launch_bounds__(512, 8) void layer_kernel(
    const ushort* __restrict__ xin, const ushort* __restrict__ x0b,
    const ushort* __restrict__ pb, const ushort* __restrict__ rlp,
    const int* __restrict__ rowptr, const int2* __restrict__ csr,
    const ushort* __restrict__ Wp,
    const ushort* __restrict__ Wp1, const float* __restrict__ b1,
    ushort* __restrict__ xout, float* __restrict__ out, float beta) {
    __shared__ ushort ts[32 * 128];   // combined-t tile (swizzled)
    __shared__ ushort prs[32 * 128];  // pr result tile (swizzled)
    const int lane = threadIdx.x & 63;
    const int wv = __builtin_amdgcn_readfirstlane(threadIdx.x >> 6);
    const int rowbase = blockIdx.x * 32;
    const int sub = lane >> 4, r16 = lane & 15;
    const int sw = (r16 & 7) << 4;
    // ---- pr MFMA: A-frags direct from packed global (same addrs all waves -> broadcast) ----
    {
        const ushort* pbt = pb + (size_t)blockIdx.x * 2048;
        float4v pacc[2] = {};
        #pragma unroll
        for (int ks = 0; ks < 2; ks++) {
            int gb = (ks * 4 + sub) * 256 + r16 * 8;
            short8v a0 = *(const short8v*)(pbt + gb);
            short8v a1 = *(const short8v*)(pbt + gb + 128);
            short8v bb = *(const short8v*)(rlp + (ks * 4 + sub) * 1024 + (16 * wv + r16) * 8);
            pacc[0] = __builtin_amdgcn_mfma_f32_16x16x32_bf16(a0, bb, pacc[0], 0, 0, 0);
            pacc[1] = __builtin_amdgcn_mfma_f32_16x16x32_bf16(a1, bb, pacc[1], 0, 0, 0);
        }
        int col = 16 * wv + r16;
        #pragma unroll
        for (int mi = 0; mi < 2; mi++)
            #pragma unroll
            for (int r = 0; r < 4; r++) {
                int rl_ = mi * 16 + sub * 4 + r;
                *(ushort*)((char*)prs + ((rl_ * 256 + col * 2) ^ ((rl_ & 7) << 4))) =
                    f2bf(pacc[mi][r]);
            }
    }
    __syncthreads();
    // ---- gather + combine -> ts (clamped full batches: one wait per 8 edges) ----
    const int nn0 = rowbase + 4 * wv;
    int rp0 = __builtin_amdgcn_readfirstlane(rowptr[nn0]);
    int rp1 = __builtin_amdgcn_readfirstlane(rowptr[nn0 + 1]);
    int rp2 = __builtin_amdgcn_readfirstlane(rowptr[nn0 + 2]);
    int rp3 = __builtin_amdgcn_readfirstlane(rowptr[nn0 + 3]);
    int rp4 = __builtin_amdgcn_readfirstlane(rowptr[nn0 + 4]);
    int rps[5] = {rp0, rp1, rp2, rp3, rp4};
    #pragma unroll 1
    for (int k = 0; k < 4; k++) {
        int rloc = 4 * wv + k;
        int nn = nn0 + k;
        int beg = rps[k], end = rps[k + 1];
        // issue residual loads early (independent of edge loop)
        ushort2 xc = *(const ushort2*)(xin + (size_t)nn * HH + 2 * lane);
        ushort2 xo = *(const ushort2*)(x0b + (size_t)nn * HH + 2 * lane);
        float accx = 0.0f, accy = 0.0f;
        int lim = end - 1;
        #pragma unroll 1
        for (int e2 = beg; e2 < end; e2 += 8) {
            int2 ed[8];
            #pragma unroll
            for (int u = 0; u < 8; u++) {
                int idx = e2 + u;
                ed[u] = csr[idx < end ? idx : lim];
            }
            ushort2 vv[8];
            #pragma unroll
            for (int u = 0; u < 8; u++)
                vv[u] = *(const ushort2*)(xin + (size_t)ed[u].x * HH + 2 * lane);
            #pragma unroll
            for (int u = 0; u < 8; u++) {
                float w = (e2 + u < end) ? __int_as_float(ed[u].y) : 0.0f;
                accx = fmaf(w, b2f(vv[u].x), accx);
                accy = fmaf(w, b2f(vv[u].y), accy);
            }
        }
        int poff = (rloc * 256 + lane * 4) ^ ((rloc & 7) << 4);
        ushort2 pv = *(const ushort2*)((const char*)prs + poff);
        ushort2 o;
        o.x = f2bf(0.45f * b2f(xc.x) + 0.45f * b2f(pv.x) + 0.45f * accx + 0.1f * b2f(xo.x));
        o.y = f2bf(0.45f * b2f(xc.y) + 0.45f * b2f(pv.y) + 0.45f * accy + 0.1f * b2f(xo.y));
        *(ushort2*)((char*)ts + poff) = o;
    }
    __syncthreads();
    // ---- conv MFMA: wave wv owns cols [16wv,16wv+16); B-frags from L2 ----
    const char* tsc = (const char*)ts;
    float4v acc[2] = {};
    #pragma unroll
    for (int ks = 0; ks < 4; ks++) {
        short8v a0 = *(const short8v*)(tsc + ((r16 * 256 + ks * 64 + sub * 16) ^ sw));
        short8v a1 = *(const short8v*)(tsc + (((16 + r16) * 256 + ks * 64 + sub * 16) ^ sw));
        short8v bb = *(const short8v*)(Wp + (ks * 4 + sub) * 1024 + (16 * wv + r16) * 8);
        acc[0] = __builtin_amdgcn_mfma_f32_16x16x32_bf16(a0, bb, acc[0], 0, 0, 0);
        acc[1] = __builtin_amdgcn_mfma_f32_16x16x32_bf16(a1, bb, acc[1], 0, 0, 0);
    }
    const float omb = 1.0f - beta;
    const int col = 16 * wv + r16;
    if constexpr (!FINAL) {
        #pragma unroll
        for (int mi = 0; mi < 2; mi++)
            #pragma unroll
            for (int r = 0; r < 4; r++) {
                int rl_ = mi * 16 + sub * 4 + r;
                int toff = (rl_ * 256 + col * 2) ^ ((rl_ & 7) << 4);
                float tv = b2f(*(const ushort*)(tsc + toff));
                float v = fmaxf(omb * tv + beta * acc[mi][r], 0.0f);
                xout[(size_t)(rowbase + rl_) * HH + col] = f2bf(v);
            }
    } else {
        __syncthreads();
        #pragma unroll
        for (int mi = 0; mi < 2; mi++)
            #pragma unroll
            for (int r = 0; r < 4; r++) {
                int rl_ = mi * 16 + sub * 4 + r;
                int toff = (rl_ * 256 + col * 2) ^ ((rl_ & 7) << 4);
                ushort* slot = (ushort*)((char*)ts + toff);
                float tv = b2f(*slot);
                float v = fmaxf(omb * tv + beta * acc[mi][r], 0.0f);
                *slot = f2bf(v);
            }
        __syncthreads();
        if (wv < 3) {
            float4v a2[2] = {};
            #pragma unroll
            for (int ks = 0; ks < 4; ks++) {
                short8v a0 = *(const short8v*)(tsc + ((r16 * 256 + ks * 64 + sub * 16) ^ sw));
                short8v a1 = *(const short8v*)(tsc + (((16 + r16) * 256 + ks * 64 + sub * 16) ^ sw));
                short8v bb = *(const short8v*)(Wp1 + (ks * 4 + sub) * 384 + (wv * 16 + r16) * 8);
                a2[0] = __builtin_amdgcn_mfma_f32_16x16x32_bf16(a0, bb, a2[0], 0, 0, 0);
                a2[1] = __builtin_amdgcn_mfma_f32_16x16x32_bf16(a1, bb, a2[1], 0, 0, 0);
            }
            int col2 = wv * 16 + r16;
            if (col2 < CC) {
                float bias = b1[col2];
                #pragma unroll
                for (int mi = 0; mi < 2; mi++)
                    #pragma unroll
                    for (int r = 0; r < 4; r++) {
                        int row = rowbase + mi * 16 + sub * 4 + r;
                        out[(size_t)row * CC + col2] = a2[mi][r] + bias;
                    }
            }
        }
    }
}

extern "C" void kernel_launch(void* const* d_in, const int* in_sizes, int n_in,
                              void* d_out, int out_size, void* d_ws, size_t ws_size,
                              hipStream_t stream) {
    const float* x_in   = (const float*)d_in[0];
    const int*   ei     = (const int*)d_in[1];
    const float* ew     = (const float*)d_in[2];
    const int*   label  = (const int*)d_in[3];
    const float* p      = (const float*)d_in[4];
    const float* cm     = (const float*)d_in[5];
    const float* lin0_w = (const float*)d_in[6];
    const float* lin0_b = (const float*)d_in[7];
    const float* lin1_w = (const float*)d_in[8];
    const float* lin1_b = (const float*)d_in[9];
    const float* conv_w = (const float*)d_in[10];
    float* out = (float*)d_out;

    const int* src = ei;
    const int* dst = ei + EE;

    const size_t NH = (size_t)NN * HH;
    float* ws = (float*)d_ws;
    // ---- zero zone (contiguous): sums0, sumsxs[3], rlp, deg, lcnt ----
    float* sums0  = ws;                        // CH
    float* sumsxs = sums0 + CH;                // 3*CH
    ushort* rlp   = (ushort*)(sumsxs + 3 * CH);// 8192 ushorts = 4096 f32
    int*   deg    = (int*)(rlp + 8192);        // NN
    int*   lcnt   = deg + NN;                  // 64
    const int ZTOT = CH + 3 * CH + 4096 + NN + 64;
    // ---- rest ----
    float* cnt    = (float*)(lcnt + 64);       // 64
    int*   rowptr = (int*)(cnt + 64);          // NN+1 (+pad)
    int*   bsum   = rowptr + NN + 64;          // 256
    int*   bcur   = bsum + 256;                // 512
    int*   lbase  = bcur + 512;                // 64
    int*   gcur   = lbase + 64;                // 64
    int*   perm   = gcur + 64;                 // NN
    int2*  csr    = (int2*)(perm + NN);        // EE
    int2*  stage  = csr + EE;                  // EE
    ushort* x0b   = (ushort*)(stage + EE);     // NH bf16
    ushort* xbA   = x0b + NH;                  // NH bf16
    ushort* xbB   = xbA + NH;                  // NH bf16
    ushort* wp0   = xbB + NH;                  // 16384
    ushort* wpc   = wp0 + 16384;               // 4*16384
    ushort* wp1   = wpc + 4 * 16384;           // 6144 (pad to 8192)
    ushort* pb    = wp1 + 8192;                // PBN (12.8 MB)

    // ---- prep: zero + pack weights; pack p ----
    prep_kernel<<<512, 256, 0, stream>>>(lin0_w, conv_w, lin1_w, wp0, wpc, wp1, (int*)ws, ZTOT);
    pack_p_kernel<<<(PBN + 255) / 256, 256, 0, stream>>>(p, pb);

    // ---- CSR + label-sort build ----
    hist2_kernel<<<(EE + 255) / 256, 256, 0, stream>>>(dst, deg, label, lcnt, EE, NN);
    const int NBLK = (NN + 511) / 512;
    scan_block_kernel<<<NBLK, 256, 0, stream>>>(deg, rowptr, bsum, NN);
    scan2_kernel<<<2, 256, 0, stream>>>(bsum, NBLK, lcnt, lbase, gcur, cnt);
    addoff_init_kernel<<<(NN + 255) / 256, 256, 0, stream>>>(rowptr, bsum, bcur, NN);
    coarse_fill_kernel<<<(EE + CHUNK - 1) / CHUNK, 256, 0, stream>>>(src, dst, ew, bcur, stage, EE);
    fine_fill_kernel<<<NB, 256, 0, stream>>>(stage, rowptr, csr, NN);
    lfill_kernel<<<256, 256, 0, stream>>>(label, lbase, gcur, perm, NN);

    // input linear + relu
    lin0_mfma_kernel<<<NN / 32, 256, 0, stream>>>(x_in, wp0, lin0_b, x0b, xbA);

    // sums0 = sum_label x0  (1563 blocks -> 16 nodes/wave = 2 full batches, 76% concurrency)
    psum_kernel<<<1563, 256, 0, stream>>>(x0b, perm, sums0, NN);

    const float betas[4] = {logf(0.5f / 1.0f + 1.0f), logf(0.5f / 2.0f + 1.0f),
                            logf(0.5f / 3.0f + 1.0f), logf(0.5f / 4.0f + 1.0f)};

    ushort* xin_b = xbA;
    ushort* xout_b = xbB;
    for (int i = 0; i < 4; i++) {
        if (i == 0) {
            cr_kernel<<<CC, 64, 0, stream>>>(sums0, sums0, cnt, cm, rlp);
        } else {
            float* sx = sumsxs + (size_t)(i - 1) * CH;
            psum_kernel<<<1563, 256, 0, stream>>>(xin_b, perm, sx, NN);
            cr_kernel<<<CC, 64, 0, stream>>>(sx, sums0, cnt, cm, rlp);
        }
        if (i < 3) {
            layer_kernel<0><<<NN / 32, 512, 0, stream>>>(xin_b, x0b, pb, rlp, rowptr, csr,
                                                         wpc + (size_t)i * 16384, wp1, lin1_b,
                                                         xout_b, out, betas[i]);
            ushort* tmp = xin_b; xin_b = xout_b; xout_b = tmp;
        } else {
            layer_kernel<1><<<NN / 32, 512, 0, stream>>>(xin_b, x0b, pb, rlp, rowptr, csr,
                                                         wpc + 3 * 16384, wp1, lin1_b,
                                                         xout_b, out, betas[3]);
        }
    }
}

// Round 18
// 461.692 us; speedup vs baseline: 1.0549x; 1.0549x over previous
//
#include <hip/hip_runtime.h>
#include <math.h>

#define NN 100000
#define EE 800000
#define CC 47
#define HH 128
#define NB 391      // node buckets of 256
#define CHUNK 2000  // edges per coarse block
#define CH (CC * HH)
#define PACKN (5 * 16384 + 6144)
#define PBN (3125 * 2048)   // p packed in A-frag order
#define PPARTS 16

typedef __attribute__((ext_vector_type(8))) short short8v;
typedef __attribute__((ext_vector_type(4))) float float4v;

__device__ inline ushort f2bf(float f) {
    unsigned u = __float_as_uint(f);
    unsigned r = (u + 0x7fffu + ((u >> 16) & 1u)) >> 16;  // RNE
    return (ushort)r;
}
__device__ inline float b2f(ushort u) { return __uint_as_float(((unsigned)u) << 16); }

// ---------------- prep: zero accumulators + pack all weights (one launch) ----------------
__global__ __launch_bounds__(256) void prep_kernel(const float* __restrict__ lin0_w,
                                                   const float* __restrict__ conv_w,
                                                   const float* __restrict__ W1,
                                                   ushort* __restrict__ wp0,
                                                   ushort* __restrict__ wpc,
                                                   ushort* __restrict__ wp1,
                                                   int* __restrict__ z, int ztot) {
    int idx = blockIdx.x * 256 + threadIdx.x;
    int stride = gridDim.x * 256;
    for (int i = idx; i < ztot; i += stride) z[i] = 0;
    for (int i = idx; i < PACKN; i += stride) {
        if (i < 5 * 16384) {
            int m = i >> 14;
            int r = i & 16383;
            int k = r >> 7, c = r & 127;
            const float* W = (m == 0) ? lin0_w : conv_w + (size_t)(m - 1) * 16384;
            ushort* Wp = (m == 0) ? wp0 : wpc + (size_t)(m - 1) * 16384;
            Wp[(k >> 3) * 1024 + c * 8 + (k & 7)] = f2bf(W[r]);
        } else {
            int j = i - 5 * 16384;
            int ksub = j / 384, rem = j - ksub * 384;
            int c = rem >> 3, kk = ksub * 8 + (rem & 7);
            wp1[j] = (c < CC) ? f2bf(W1[kk * CC + c]) : (ushort)0;
        }
    }
}

// ---------------- pack p [N][47] f32 -> per-tile MFMA A-fragment order bf16 ----------------
__global__ __launch_bounds__(256) void pack_p_kernel(const float* __restrict__ p,
                                                     ushort* __restrict__ pb) {
    int idx = blockIdx.x * 256 + threadIdx.x;
    if (idx >= PBN) return;
    int t = idx >> 11;
    int rem = idx & 2047;
    int grp = rem >> 8;          // ks*4+sub
    int rem2 = rem & 255;
    int half = rem2 >> 7;
    int r16 = (rem2 >> 3) & 15;
    int j = rem2 & 7;
    int row = t * 32 + half * 16 + r16;
    int k = (grp >> 2) * 32 + (grp & 3) * 8 + j;
    pb[idx] = (k < CC) ? f2bf(p[(size_t)row * CC + k]) : (ushort)0;
}

// ---------------- fused histograms: edge-degree + label counts ----------------
__global__ __launch_bounds__(256) void hist2_kernel(const int* __restrict__ dst,
                                                    int* __restrict__ deg,
                                                    const int* __restrict__ label,
                                                    int* __restrict__ lcnt, int e, int n) {
    __shared__ int lh[CC];
    int t = threadIdx.x;
    if (t < CC) lh[t] = 0;
    __syncthreads();
    int i = blockIdx.x * 256 + t;
    if (i < e) atomicAdd(&deg[dst[i]], 1);
    bool has = blockIdx.x < (unsigned)((n + 255) / 256);
    if (has && i < n) atomicAdd(&lh[label[i]], 1);
    __syncthreads();
    if (has && t < CC && lh[t] > 0) atomicAdd(&lcnt[t], lh[t]);
}

__global__ __launch_bounds__(256) void scan_block_kernel(const int* __restrict__ deg,
                                                         int* __restrict__ rowptr,
                                                         int* __restrict__ bsum, int n) {
    __shared__ int ls[256];
    int b = blockIdx.x, t = threadIdx.x;
    int i0 = b * 512 + 2 * t;
    int a0 = (i0 < n) ? deg[i0] : 0;
    int a1 = (i0 + 1 < n) ? deg[i0 + 1] : 0;
    int val = a0 + a1;
    ls[t] = val;
    __syncthreads();
    for (int off = 1; off < 256; off <<= 1) {
        int add = (t >= off) ? ls[t - off] : 0;
        __syncthreads();
        val += add;
        ls[t] = val;
        __syncthreads();
    }
    int incl1 = val;
    int incl0 = val - a1;
    if (i0 < n) rowptr[i0 + 1] = incl0;
    if (i0 + 1 < n) rowptr[i0 + 2] = incl1;
    if (t == 255) bsum[b] = val;
}

// block 0: exclusive block-offset scan of bsum; block 1: label scan + cnt float copy
__global__ __launch_bounds__(256) void scan2_kernel(int* __restrict__ bsum, int nb,
                                                    const int* __restrict__ lcnt,
                                                    int* __restrict__ lbase,
                                                    int* __restrict__ gcur,
                                                    float* __restrict__ cntf) {
    if (blockIdx.x == 0) {
        __shared__ int ls[256];
        int t = threadIdx.x;
        int v = (t < nb) ? bsum[t] : 0;
        int orig = v;
        ls[t] = v;
        __syncthreads();
        for (int off = 1; off < 256; off <<= 1) {
            int add = (t >= off) ? ls[t - off] : 0;
            __syncthreads();
            v += add;
            ls[t] = v;
            __syncthreads();
        }
        if (t < nb) bsum[t] = v - orig;
    } else {
        __shared__ int ls[CC];
        int t = threadIdx.x;
        if (t < CC) {
            int v = lcnt[t];
            cntf[t] = (float)v;
            gcur[t] = 0;
            ls[t] = v;
        }
        __syncthreads();
        if (t == 0) {
            int run = 0;
            for (int c = 0; c < CC; c++) { int x = ls[c]; ls[c] = run; run += x; }
        }
        __syncthreads();
        if (t < CC) lbase[t] = ls[t];
    }
}

// add block offsets to rowptr AND compute bucket cursors analytically (race-free)
__global__ __launch_bounds__(256) void addoff_init_kernel(int* __restrict__ rowptr,
                                                          const int* __restrict__ bsum,
                                                          int* __restrict__ bcur, int n) {
    int i = blockIdx.x * 256 + threadIdx.x;
    if (i < n) {
        int v = rowptr[i + 1] + bsum[i >> 9];
        rowptr[i + 1] = v;
        if (((i + 1) & 255) == 0 && ((i + 1) >> 8) < 512) bcur[(i + 1) >> 8] = v;
    }
    if (i == 0) { rowptr[0] = 0; bcur[0] = 0; }
    if (i < 512 && i * 256 >= n) bcur[i] = EE;
}

// ---------------- binned CSR fill ----------------
__global__ __launch_bounds__(256) void coarse_fill_kernel(const int* __restrict__ src,
                                                          const int* __restrict__ dst,
                                                          const float* __restrict__ ew,
                                                          int* __restrict__ bcur,
                                                          int2* __restrict__ stage, int e) {
    __shared__ int hist[512];
    __shared__ int base_local[512];
    __shared__ int gbase[512];
    __shared__ int lc[512];
    __shared__ int ls[256];
    __shared__ int2 le[CHUNK];
    __shared__ ushort lb[CHUNK];
    int t = threadIdx.x;
    int beg = blockIdx.x * CHUNK, end = min(e, beg + CHUNK);
    int cnt = end - beg;
    for (int i = t; i < 512; i += 256) { hist[i] = 0; lc[i] = 0; }
    __syncthreads();
    for (int i = beg + t; i < end; i += 256) atomicAdd(&hist[((unsigned)dst[i]) >> 8], 1);
    __syncthreads();
    int a0 = hist[2 * t], a1 = hist[2 * t + 1];
    int val = a0 + a1;
    ls[t] = val;
    __syncthreads();
    for (int off = 1; off < 256; off <<= 1) {
        int add = (t >= off) ? ls[t - off] : 0;
        __syncthreads();
        val += add;
        ls[t] = val;
        __syncthreads();
    }
    base_local[2 * t] = val - a0 - a1;
    base_local[2 * t + 1] = val - a1;
    __syncthreads();
    for (int b = t; b < 512; b += 256)
        if (hist[b] > 0) gbase[b] = atomicAdd(&bcur[b], hist[b]);
    __syncthreads();
    for (int i = beg + t; i < end; i += 256) {
        int d = dst[i];
        int bk = ((unsigned)d) >> 8;
        int slot = base_local[bk] + atomicAdd(&lc[bk], 1);
        le[slot] = make_int2(((d & 255) << 24) | src[i], __float_as_int(ew[i]));
        lb[slot] = (ushort)bk;
    }
    __syncthreads();
    for (int s = t; s < cnt; s += 256) {
        int bk = lb[s];
        stage[gbase[bk] + (s - base_local[bk])] = le[s];
    }
}

__global__ __launch_bounds__(256) void fine_fill_kernel(const int2* __restrict__ stage,
                                                        const int* __restrict__ rowptr,
                                                        int2* __restrict__ csr, int n) {
    __shared__ int cur[256];
    __shared__ int rp[257];
    int b = blockIdx.x, t = threadIdx.x;
    int node0 = b * 256;
    int nodes = min(256, n - node0);
    cur[t] = 0;
    rp[t] = rowptr[min(node0 + t, n)];
    if (t == 0) rp[256] = rowptr[min(node0 + 256, n)];
    __syncthreads();
    int S = rp[0], E = rp[nodes];
    for (int i = S + t; i < E; i += 256) {
        int2 en = stage[i];
        int dl = ((unsigned)en.x) >> 24;
        int pos = rp[dl] + atomicAdd(&cur[dl], 1);
        csr[pos] = make_int2(en.x & 0xFFFFFF, en.y);
    }
}

__global__ __launch_bounds__(256) void lfill_kernel(const int* __restrict__ label,
                                                    const int* __restrict__ lbase,
                                                    int* __restrict__ gcur,
                                                    int* __restrict__ perm, int n) {
    __shared__ int lh[CC], lbs[CC], lc[CC];
    int t = threadIdx.x;
    if (t < CC) lh[t] = 0;
    __syncthreads();
    int chunk = (n + gridDim.x - 1) / gridDim.x;
    int beg = blockIdx.x * chunk, end = min(n, beg + chunk);
    for (int i = beg + t; i < end; i += 256) atomicAdd(&lh[label[i]], 1);
    __syncthreads();
    if (t < CC) {
        lbs[t] = (lh[t] > 0) ? atomicAdd(&gcur[t], lh[t]) : 0;
        lc[t] = 0;
    }
    __syncthreads();
    for (int i = beg + t; i < end; i += 256) {
        int c = label[i];
        int pos = atomicAdd(&lc[c], 1);
        perm[lbase[c] + lbs[c] + pos] = (c << 24) | i;
    }
}

// ---------------- segment sums: one label per block-group (no label checks, 2 atomics/lane) ----------------
__global__ __launch_bounds__(256) void psum2_kernel(const ushort* __restrict__ xb,
                                                    const int* __restrict__ perm,
                                                    const int* __restrict__ lbase,
                                                    const int* __restrict__ lcnt,
                                                    float* __restrict__ sums) {
    int c = blockIdx.x / PPARTS;
    int part = blockIdx.x % PPARTS;
    int base = lbase[c], cnt = lcnt[c];
    int chunk = (cnt + PPARTS - 1) / PPARTS;
    int sbeg = part * chunk, send = min(cnt, sbeg + chunk);
    if (sbeg >= send) return;
    const int lane = threadIdx.x & 63;
    const int wid = threadIdx.x >> 6;
    int wlen = send - sbeg;
    int wchunk = (wlen + 3) / 4;
    int beg = base + sbeg + wid * wchunk;
    int end = min(base + send, beg + wchunk);
    if (beg >= end) return;
    float ax = 0.0f, ay = 0.0f;
    int lim = end - 1;
    #pragma unroll 1
    for (int i = beg; i < end; i += 8) {
        int pp[8];
        #pragma unroll
        for (int u = 0; u < 8; u++) {
            int idx = i + u;
            pp[u] = perm[idx < end ? idx : lim];
        }
        ushort2 vv[8];
        #pragma unroll
        for (int u = 0; u < 8; u++)
            vv[u] = *(const ushort2*)(xb + (size_t)(pp[u] & 0xFFFFFF) * HH + 2 * lane);
        #pragma unroll
        for (int u = 0; u < 8; u++) {
            bool ok = (i + u < end);
            ax += ok ? b2f(vv[u].x) : 0.0f;
            ay += ok ? b2f(vv[u].y) : 0.0f;
        }
    }
    atomicAdd(&sums[c * HH + 2 * lane], ax);
    atomicAdd(&sums[c * HH + 2 * lane + 1], ay);
}

// ---------------- lin0 (B-frags from L2) ----------------
__global__ __launch_bounds__(256) void lin0_mfma_kernel(const float* __restrict__ xin,
                                                        const ushort* __restrict__ Wp,
                                                        const float* __restrict__ bias,
                                                        ushort* __restrict__ x0b,
                                                        ushort* __restrict__ xb) {
    __shared__ ushort ts[32 * 128];
    const int lane = threadIdx.x & 63, wv = threadIdx.x >> 6;
    const int sub = lane >> 4, r16 = lane & 15;
    const int wbase = wv * 32;
    const int rowbase = blockIdx.x * 32;
    const float* tp = xin + (size_t)rowbase * HH;
    #pragma unroll
    for (int j = 0; j < 4; j++) {
        int e = 4 * threadIdx.x + j * 1024;
        float4 f = *(const float4*)(tp + e);
        int r = e >> 7, c = e & 127;
        ushort4 b4 = make_ushort4(f2bf(f.x), f2bf(f.y), f2bf(f.z), f2bf(f.w));
        int off = (r * 256 + c * 2) ^ ((r & 7) << 4);
        *(ushort4*)((char*)ts + off) = b4;
    }
    __syncthreads();
    float4v acc[2][2] = {};
    {
        const char* tsc = (const char*)ts;
        const int sw = (r16 & 7) << 4;
        #pragma unroll
        for (int ks = 0; ks < 4; ks++) {
            short8v a0 = *(const short8v*)(tsc + ((r16 * 256 + ks * 64 + sub * 16) ^ sw));
            short8v a1 = *(const short8v*)(tsc + (((16 + r16) * 256 + ks * 64 + sub * 16) ^ sw));
            int kb = (ks * 4 + sub) * 1024;
            short8v b0 = *(const short8v*)(Wp + kb + (wbase + r16) * 8);
            short8v b1 = *(const short8v*)(Wp + kb + (wbase + 16 + r16) * 8);
            acc[0][0] = __builtin_amdgcn_mfma_f32_16x16x32_bf16(a0, b0, acc[0][0], 0, 0, 0);
            acc[0][1] = __builtin_amdgcn_mfma_f32_16x16x32_bf16(a0, b1, acc[0][1], 0, 0, 0);
            acc[1][0] = __builtin_amdgcn_mfma_f32_16x16x32_bf16(a1, b0, acc[1][0], 0, 0, 0);
            acc[1][1] = __builtin_amdgcn_mfma_f32_16x16x32_bf16(a1, b1, acc[1][1], 0, 0, 0);
        }
    }
    float bv[2] = {bias[wbase + r16], bias[wbase + 16 + r16]};
    #pragma unroll
    for (int mi = 0; mi < 2; mi++)
        #pragma unroll
        for (int ni = 0; ni < 2; ni++) {
            int col = wbase + ni * 16 + r16;
            #pragma unroll
            for (int r = 0; r < 4; r++) {
                int row = rowbase + mi * 16 + sub * 4 + r;
                float v = fmaxf(acc[mi][ni][r] + bv[ni], 0.0f);
                ushort bv16 = f2bf(v);
                x0b[(size_t)row * HH + col] = bv16;
                xb[(size_t)row * HH + col] = bv16;
            }
        }
}

// ---------------- fused centers + rcm + pack ----------------
__global__ __launch_bounds__(64) void cr_kernel(const float* __restrict__ sumsx,
                                                const float* __restrict__ sums0,
                                                const float* __restrict__ cnt,
                                                const float* __restrict__ cm,
                                                ushort* __restrict__ rlp) {
    __shared__ float cs[CC * HH];
    int i = blockIdx.x, lane = threadIdx.x;
    for (int idx = lane; idx < CC * HH; idx += 64) {
        int c = idx >> 7;
        cs[idx] = (sumsx[idx] + 0.1f * sums0[idx]) / fmaxf(cnt[c], 1.0f);
    }
    __syncthreads();
    float ci0 = cs[i * HH + lane];
    float ci1 = cs[i * HH + 64 + lane];
    float acc0 = 0.0f, acc1 = 0.0f;
    for (int j = 0; j < CC; j++) {
        float d0 = ci0 - cs[j * HH + lane];
        float d1 = ci1 - cs[j * HH + 64 + lane];
        float s = d0 * d0 + d1 * d1;
        #pragma unroll
        for (int off = 32; off >= 1; off >>= 1) s += __shfl_xor(s, off);
        float nrm = sqrtf(s);
        if (nrm == 0.0f) nrm = 1.0f;
        float w = cm[i * CC + j] / nrm;
        acc0 = fmaf(w, d0, acc0);
        acc1 = fmaf(w, d1, acc1);
    }
    rlp[(i >> 3) * 1024 + lane * 8 + (i & 7)] = f2bf(acc0);
    rlp[(i >> 3) * 1024 + (lane + 64) * 8 + (i & 7)] = f2bf(acc1);
}

// ---------------- fused layer: pr MFMA (A from packed global) + gather/combine + conv MFMA ----------------
template <int FINAL>
__global__ __launch_bounds__(512, 8) void layer_kernel(
    const ushort* __restrict__ xin, const ushort* __restrict__ x0b,
    const ushort* __restrict__ pb, const ushort* __restrict__ rlp,
    const int* __restrict__ rowptr, const int2* __restrict__ csr,
    const ushort* __restrict__ Wp,
    const ushort* __restrict__ Wp1, const float* __restrict__ b1,
    ushort* __restrict__ xout, float* __restrict__ out, float beta) {
    __shared__ ushort ts[32 * 128];   // combined-t tile (swizzled)
    __shared__ ushort prs[32 * 128];  // pr result tile (swizzled)
    const int lane = threadIdx.x & 63;
    const int wv = __builtin_amdgcn_readfirstlane(threadIdx.x >> 6);
    const int rowbase = blockIdx.x * 32;
    const int sub = lane >> 4, r16 = lane & 15;
    const int sw = (r16 & 7) << 4;
    // ---- pr MFMA: A-frags direct from packed global (same addrs all waves -> broadcast) ----
    {
        const ushort* pbt = pb + (size_t)blockIdx.x * 2048;
        float4v pacc[2] = {};
        #pragma unroll
        for (int ks = 0; ks < 2; ks++) {
            int gb = (ks * 4 + sub) * 256 + r16 * 8;
            short8v a0 = *(const short8v*)(pbt + gb);
            short8v a1 = *(const short8v*)(pbt + gb + 128);
            short8v bb = *(const short8v*)(rlp + (ks * 4 + sub) * 1024 + (16 * wv + r16) * 8);
            pacc[0] = __builtin_amdgcn_mfma_f32_16x16x32_bf16(a0, bb, pacc[0], 0, 0, 0);
            pacc[1] = __builtin_amdgcn_mfma_f32_16x16x32_bf16(a1, bb, pacc[1], 0, 0, 0);
        }
        int col = 16 * wv + r16;
        #pragma unroll
        for (int mi = 0; mi < 2; mi++)
            #pragma unroll
            for (int r = 0; r < 4; r++) {
                int rl_ = mi * 16 + sub * 4 + r;
                *(ushort*)((char*)prs + ((rl_ * 256 + col * 2) ^ ((rl_ & 7) << 4))) =
                    f2bf(pacc[mi][r]);
            }
    }
    __syncthreads();
    // ---- gather + combine -> ts (clamped full batches: one wait per 8 edges) ----
    const int nn0 = rowbase + 4 * wv;
    int rp0 = __builtin_amdgcn_readfirstlane(rowptr[nn0]);
    int rp1 = __builtin_amdgcn_readfirstlane(rowptr[nn0 + 1]);
    int rp2 = __builtin_amdgcn_readfirstlane(rowptr[nn0 + 2]);
    int rp3 = __builtin_amdgcn_readfirstlane(rowptr[nn0 + 3]);
    int rp4 = __builtin_amdgcn_readfirstlane(rowptr[nn0 + 4]);
    int rps[5] = {rp0, rp1, rp2, rp3, rp4};
    #pragma unroll 1
    for (int k = 0; k < 4; k++) {
        int rloc = 4 * wv + k;
        int nn = nn0 + k;
        int beg = rps[k], end = rps[k + 1];
        // issue residual loads early (independent of edge loop)
        ushort2 xc = *(const ushort2*)(xin + (size_t)nn * HH + 2 * lane);
        ushort2 xo = *(const ushort2*)(x0b + (size_t)nn * HH + 2 * lane);
        float accx = 0.0f, accy = 0.0f;
        int lim = end - 1;
        #pragma unroll 1
        for (int e2 = beg; e2 < end; e2 += 8) {
            int2 ed[8];
            #pragma unroll
            for (int u = 0; u < 8; u++) {
                int idx = e2 + u;
                ed[u] = csr[idx < end ? idx : lim];
            }
            ushort2 vv[8];
            #pragma unroll
            for (int u = 0; u < 8; u++)
                vv[u] = *(const ushort2*)(xin + (size_t)ed[u].x * HH + 2 * lane);
            #pragma unroll
            for (int u = 0; u < 8; u++) {
                float w = (e2 + u < end) ? __int_as_float(ed[u].y) : 0.0f;
                accx = fmaf(w, b2f(vv[u].x), accx);
                accy = fmaf(w, b2f(vv[u].y), accy);
            }
        }
        int poff = (rloc * 256 + lane * 4) ^ ((rloc & 7) << 4);
        ushort2 pv = *(const ushort2*)((const char*)prs + poff);
        ushort2 o;
        o.x = f2bf(0.45f * b2f(xc.x) + 0.45f * b2f(pv.x) + 0.45f * accx + 0.1f * b2f(xo.x));
        o.y = f2bf(0.45f * b2f(xc.y) + 0.45f * b2f(pv.y) + 0.45f * accy + 0.1f * b2f(xo.y));
        *(ushort2*)((char*)ts + poff) = o;
    }
    __syncthreads();
    // ---- conv MFMA: wave wv owns cols [16wv,16wv+16); B-frags from L2 ----
    const char* tsc = (const char*)ts;
    float4v acc[2] = {};
    #pragma unroll
    for (int ks = 0; ks < 4; ks++) {
        short8v a0 = *(const short8v*)(tsc + ((r16 * 256 + ks * 64 + sub * 16) ^ sw));
        short8v a1 = *(const short8v*)(tsc + (((16 + r16) * 256 + ks * 64 + sub * 16) ^ sw));
        short8v bb = *(const short8v*)(Wp + (ks * 4 + sub) * 1024 + (16 * wv + r16) * 8);
        acc[0] = __builtin_amdgcn_mfma_f32_16x16x32_bf16(a0, bb, acc[0], 0, 0, 0);
        acc[1] = __builtin_amdgcn_mfma_f32_16x16x32_bf16(a1, bb, acc[1], 0, 0, 0);
    }
    const float omb = 1.0f - beta;
    const int col = 16 * wv + r16;
    if constexpr (!FINAL) {
        #pragma unroll
        for (int mi = 0; mi < 2; mi++)
            #pragma unroll
            for (int r = 0; r < 4; r++) {
                int rl_ = mi * 16 + sub * 4 + r;
                int toff = (rl_ * 256 + col * 2) ^ ((rl_ & 7) << 4);
                float tv = b2f(*(const ushort*)(tsc + toff));
                float v = fmaxf(omb * tv + beta * acc[mi][r], 0.0f);
                xout[(size_t)(rowbase + rl_) * HH + col] = f2bf(v);
            }
    } else {
        __syncthreads();
        #pragma unroll
        for (int mi = 0; mi < 2; mi++)
            #pragma unroll
            for (int r = 0; r < 4; r++) {
                int rl_ = mi * 16 + sub * 4 + r;
                int toff = (rl_ * 256 + col * 2) ^ ((rl_ & 7) << 4);
                ushort* slot = (ushort*)((char*)ts + toff);
                float tv = b2f(*slot);
                float v = fmaxf(omb * tv + beta * acc[mi][r], 0.0f);
                *slot = f2bf(v);
            }
        __syncthreads();
        if (wv < 3) {
            float4v a2[2] = {};
            #pragma unroll
            for (int ks = 0; ks < 4; ks++) {
                short8v a0 = *(const short8v*)(tsc + ((r16 * 256 + ks * 64 + sub * 16) ^ sw));
                short8v a1 = *(const short8v*)(tsc + (((16 + r16) * 256 + ks * 64 + sub * 16) ^ sw));
                short8v bb = *(const short8v*)(Wp1 + (ks * 4 + sub) * 384 + (wv * 16 + r16) * 8);
                a2[0] = __builtin_amdgcn_mfma_f32_16x16x32_bf16(a0, bb, a2[0], 0, 0, 0);
                a2[1] = __builtin_amdgcn_mfma_f32_16x16x32_bf16(a1, bb, a2[1], 0, 0, 0);
            }
            int col2 = wv * 16 + r16;
            if (col2 < CC) {
                float bias = b1[col2];
                #pragma unroll
                for (int mi = 0; mi < 2; mi++)
                    #pragma unroll
                    for (int r = 0; r < 4; r++) {
                        int row = rowbase + mi * 16 + sub * 4 + r;
                        out[(size_t)row * CC + col2] = a2[mi][r] + bias;
                    }
            }
        }
    }
}

extern "C" void kernel_launch(void* const* d_in, const int* in_sizes, int n_in,
                              void* d_out, int out_size, void* d_ws, size_t ws_size,
                              hipStream_t stream) {
    const float* x_in   = (const float*)d_in[0];
    const int*   ei     = (const int*)d_in[1];
    const float* ew     = (const float*)d_in[2];
    const int*   label  = (const int*)d_in[3];
    const float* p      = (const float*)d_in[4];
    const float* cm     = (const float*)d_in[5];
    const float* lin0_w = (const float*)d_in[6];
    const float* lin0_b = (const float*)d_in[7];
    const float* lin1_w = (const float*)d_in[8];
    const float* lin1_b = (const float*)d_in[9];
    const float* conv_w = (const float*)d_in[10];
    float* out = (float*)d_out;

    const int* src = ei;
    const int* dst = ei + EE;

    const size_t NH = (size_t)NN * HH;
    float* ws = (float*)d_ws;
    // ---- zero zone (contiguous): sums0, sumsxs[3], rlp, deg, lcnt ----
    float* sums0  = ws;                        // CH
    float* sumsxs = sums0 + CH;                // 3*CH
    ushort* rlp   = (ushort*)(sumsxs + 3 * CH);// 8192 ushorts = 4096 f32
    int*   deg    = (int*)(rlp + 8192);        // NN
    int*   lcnt   = deg + NN;                  // 64
    const int ZTOT = CH + 3 * CH + 4096 + NN + 64;
    // ---- rest ----
    float* cnt    = (float*)(lcnt + 64);       // 64
    int*   rowptr = (int*)(cnt + 64);          // NN+1 (+pad)
    int*   bsum   = rowptr + NN + 64;          // 256
    int*   bcur   = bsum + 256;                // 512
    int*   lbase  = bcur + 512;                // 64
    int*   gcur   = lbase + 64;                // 64
    int*   perm   = gcur + 64;                 // NN
    int2*  csr    = (int2*)(perm + NN);        // EE
    int2*  stage  = csr + EE;                  // EE
    ushort* x0b   = (ushort*)(stage + EE);     // NH bf16
    ushort* xbA   = x0b + NH;                  // NH bf16
    ushort* xbB   = xbA + NH;                  // NH bf16
    ushort* wp0   = xbB + NH;                  // 16384
    ushort* wpc   = wp0 + 16384;               // 4*16384
    ushort* wp1   = wpc + 4 * 16384;           // 6144 (pad to 8192)
    ushort* pb    = wp1 + 8192;                // PBN (12.8 MB)

    // ---- prep: zero + pack weights; pack p ----
    prep_kernel<<<512, 256, 0, stream>>>(lin0_w, conv_w, lin1_w, wp0, wpc, wp1, (int*)ws, ZTOT);
    pack_p_kernel<<<(PBN + 255) / 256, 256, 0, stream>>>(p, pb);

    // ---- CSR + label-sort build ----
    hist2_kernel<<<(EE + 255) / 256, 256, 0, stream>>>(dst, deg, label, lcnt, EE, NN);
    const int NBLK = (NN + 511) / 512;
    scan_block_kernel<<<NBLK, 256, 0, stream>>>(deg, rowptr, bsum, NN);
    scan2_kernel<<<2, 256, 0, stream>>>(bsum, NBLK, lcnt, lbase, gcur, cnt);
    addoff_init_kernel<<<(NN + 255) / 256, 256, 0, stream>>>(rowptr, bsum, bcur, NN);
    coarse_fill_kernel<<<(EE + CHUNK - 1) / CHUNK, 256, 0, stream>>>(src, dst, ew, bcur, stage, EE);
    fine_fill_kernel<<<NB, 256, 0, stream>>>(stage, rowptr, csr, NN);
    lfill_kernel<<<256, 256, 0, stream>>>(label, lbase, gcur, perm, NN);

    // input linear + relu
    lin0_mfma_kernel<<<NN / 32, 256, 0, stream>>>(x_in, wp0, lin0_b, x0b, xbA);

    // sums0 = sum_label x0  (one label per 16-block group: no label probing, 2 atomics/lane)
    psum2_kernel<<<CC * PPARTS, 256, 0, stream>>>(x0b, perm, lbase, lcnt, sums0);

    const float betas[4] = {logf(0.5f / 1.0f + 1.0f), logf(0.5f / 2.0f + 1.0f),
                            logf(0.5f / 3.0f + 1.0f), logf(0.5f / 4.0f + 1.0f)};

    ushort* xin_b = xbA;
    ushort* xout_b = xbB;
    for (int i = 0; i < 4; i++) {
        if (i == 0) {
            cr_kernel<<<CC, 64, 0, stream>>>(sums0, sums0, cnt, cm, rlp);
        } else {
            float* sx = sumsxs + (size_t)(i - 1) * CH;
            psum2_kernel<<<CC * PPARTS, 256, 0, stream>>>(xin_b, perm, lbase, lcnt, sx);
            cr_kernel<<<CC, 64, 0, stream>>>(sx, sums0, cnt, cm, rlp);
        }
        if (i < 3) {
            layer_kernel<0><<<NN / 32, 512, 0, stream>>>(xin_b, x0b, pb, rlp, rowptr, csr,
                                                         wpc + (size_t)i * 16384, wp1, lin1_b,
                                                         xout_b, out, betas[i]);
            ushort* tmp = xin_b; xin_b = xout_b; xout_b = tmp;
        } else {
            layer_kernel<1><<<NN / 32, 512, 0, stream>>>(xin_b, x0b, pb, rlp, rowptr, csr,
                                                         wpc + 3 * 16384, wp1, lin1_b,
                                                         xout_b, out, betas[3]);
        }
    }
}

// Round 19
// 455.306 us; speedup vs baseline: 1.0697x; 1.0140x over previous
//
#include <hip/hip_runtime.h>
#include <math.h>

#define NN 100000
#define EE 800000
#define CC 47
#define HH 128
#define NB 391      // node buckets of 256
#define CHUNK 2000  // edges per coarse block
#define CH (CC * HH)
#define PACKN (5 * 16384 + 6144)
#define PBN (3125 * 2048)   // p packed in A-frag order
#define PPARTS 16

typedef __attribute__((ext_vector_type(8))) short short8v;
typedef __attribute__((ext_vector_type(4))) float float4v;

__device__ inline ushort f2bf(float f) {
    unsigned u = __float_as_uint(f);
    unsigned r = (u + 0x7fffu + ((u >> 16) & 1u)) >> 16;  // RNE
    return (ushort)r;
}
__device__ inline float b2f(ushort u) { return __uint_as_float(((unsigned)u) << 16); }

// ---------------- prep: zero accumulators + pack all weights + pack p (one launch) ----------------
__global__ __launch_bounds__(256) void prep_kernel(const float* __restrict__ lin0_w,
                                                   const float* __restrict__ conv_w,
                                                   const float* __restrict__ W1,
                                                   const float* __restrict__ p,
                                                   ushort* __restrict__ wp0,
                                                   ushort* __restrict__ wpc,
                                                   ushort* __restrict__ wp1,
                                                   ushort* __restrict__ pb,
                                                   int* __restrict__ z, int ztot) {
    int idx = blockIdx.x * 256 + threadIdx.x;
    int stride = gridDim.x * 256;
    for (int i = idx; i < ztot; i += stride) z[i] = 0;
    for (int i = idx; i < PACKN; i += stride) {
        if (i < 5 * 16384) {
            int m = i >> 14;
            int r = i & 16383;
            int k = r >> 7, c = r & 127;
            const float* W = (m == 0) ? lin0_w : conv_w + (size_t)(m - 1) * 16384;
            ushort* Wp = (m == 0) ? wp0 : wpc + (size_t)(m - 1) * 16384;
            Wp[(k >> 3) * 1024 + c * 8 + (k & 7)] = f2bf(W[r]);
        } else {
            int j = i - 5 * 16384;
            int ksub = j / 384, rem = j - ksub * 384;
            int c = rem >> 3, kk = ksub * 8 + (rem & 7);
            wp1[j] = (c < CC) ? f2bf(W1[kk * CC + c]) : (ushort)0;
        }
    }
    for (int i = idx; i < PBN; i += stride) {
        int t = i >> 11;
        int rem = i & 2047;
        int grp = rem >> 8;          // ks*4+sub
        int rem2 = rem & 255;
        int half = rem2 >> 7;
        int r16 = (rem2 >> 3) & 15;
        int j = rem2 & 7;
        int row = t * 32 + half * 16 + r16;
        int k = (grp >> 2) * 32 + (grp & 3) * 8 + j;
        pb[i] = (k < CC) ? f2bf(p[(size_t)row * CC + k]) : (ushort)0;
    }
}

// ---------------- fused histograms: edge-degree + label counts ----------------
__global__ __launch_bounds__(256) void hist2_kernel(const int* __restrict__ dst,
                                                    int* __restrict__ deg,
                                                    const int* __restrict__ label,
                                                    int* __restrict__ lcnt, int e, int n) {
    __shared__ int lh[CC];
    int t = threadIdx.x;
    if (t < CC) lh[t] = 0;
    __syncthreads();
    int i = blockIdx.x * 256 + t;
    if (i < e) atomicAdd(&deg[dst[i]], 1);
    bool has = blockIdx.x < (unsigned)((n + 255) / 256);
    if (has && i < n) atomicAdd(&lh[label[i]], 1);
    __syncthreads();
    if (has && t < CC && lh[t] > 0) atomicAdd(&lcnt[t], lh[t]);
}

__global__ __launch_bounds__(256) void scan_block_kernel(const int* __restrict__ deg,
                                                         int* __restrict__ rowptr,
                                                         int* __restrict__ bsum, int n) {
    __shared__ int ls[256];
    int b = blockIdx.x, t = threadIdx.x;
    int i0 = b * 512 + 2 * t;
    int a0 = (i0 < n) ? deg[i0] : 0;
    int a1 = (i0 + 1 < n) ? deg[i0 + 1] : 0;
    int val = a0 + a1;
    ls[t] = val;
    __syncthreads();
    for (int off = 1; off < 256; off <<= 1) {
        int add = (t >= off) ? ls[t - off] : 0;
        __syncthreads();
        val += add;
        ls[t] = val;
        __syncthreads();
    }
    int incl1 = val;
    int incl0 = val - a1;
    if (i0 < n) rowptr[i0 + 1] = incl0;
    if (i0 + 1 < n) rowptr[i0 + 2] = incl1;
    if (t == 255) bsum[b] = val;
}

// block 0: exclusive block-offset scan of bsum; block 1: label scan + cnt float copy
__global__ __launch_bounds__(256) void scan2_kernel(int* __restrict__ bsum, int nb,
                                                    const int* __restrict__ lcnt,
                                                    int* __restrict__ lbase,
                                                    int* __restrict__ gcur,
                                                    float* __restrict__ cntf) {
    if (blockIdx.x == 0) {
        __shared__ int ls[256];
        int t = threadIdx.x;
        int v = (t < nb) ? bsum[t] : 0;
        int orig = v;
        ls[t] = v;
        __syncthreads();
        for (int off = 1; off < 256; off <<= 1) {
            int add = (t >= off) ? ls[t - off] : 0;
            __syncthreads();
            v += add;
            ls[t] = v;
            __syncthreads();
        }
        if (t < nb) bsum[t] = v - orig;
    } else {
        __shared__ int ls[CC];
        int t = threadIdx.x;
        if (t < CC) {
            int v = lcnt[t];
            cntf[t] = (float)v;
            gcur[t] = 0;
            ls[t] = v;
        }
        __syncthreads();
        if (t == 0) {
            int run = 0;
            for (int c = 0; c < CC; c++) { int x = ls[c]; ls[c] = run; run += x; }
        }
        __syncthreads();
        if (t < CC) lbase[t] = ls[t];
    }
}

// add block offsets to rowptr AND compute bucket cursors analytically (race-free)
__global__ __launch_bounds__(256) void addoff_init_kernel(int* __restrict__ rowptr,
                                                          const int* __restrict__ bsum,
                                                          int* __restrict__ bcur, int n) {
    int i = blockIdx.x * 256 + threadIdx.x;
    if (i < n) {
        int v = rowptr[i + 1] + bsum[i >> 9];
        rowptr[i + 1] = v;
        if (((i + 1) & 255) == 0 && ((i + 1) >> 8) < 512) bcur[(i + 1) >> 8] = v;
    }
    if (i == 0) { rowptr[0] = 0; bcur[0] = 0; }
    if (i < 512 && i * 256 >= n) bcur[i] = EE;
}

// ---------------- binned CSR fill ----------------
__global__ __launch_bounds__(256) void coarse_fill_kernel(const int* __restrict__ src,
                                                          const int* __restrict__ dst,
                                                          const float* __restrict__ ew,
                                                          int* __restrict__ bcur,
                                                          int2* __restrict__ stage, int e) {
    __shared__ int hist[512];
    __shared__ int base_local[512];
    __shared__ int gbase[512];
    __shared__ int lc[512];
    __shared__ int ls[256];
    __shared__ int2 le[CHUNK];
    __shared__ ushort lb[CHUNK];
    int t = threadIdx.x;
    int beg = blockIdx.x * CHUNK, end = min(e, beg + CHUNK);
    int cnt = end - beg;
    for (int i = t; i < 512; i += 256) { hist[i] = 0; lc[i] = 0; }
    __syncthreads();
    for (int i = beg + t; i < end; i += 256) atomicAdd(&hist[((unsigned)dst[i]) >> 8], 1);
    __syncthreads();
    int a0 = hist[2 * t], a1 = hist[2 * t + 1];
    int val = a0 + a1;
    ls[t] = val;
    __syncthreads();
    for (int off = 1; off < 256; off <<= 1) {
        int add = (t >= off) ? ls[t - off] : 0;
        __syncthreads();
        val += add;
        ls[t] = val;
        __syncthreads();
    }
    base_local[2 * t] = val - a0 - a1;
    base_local[2 * t + 1] = val - a1;
    __syncthreads();
    for (int b = t; b < 512; b += 256)
        if (hist[b] > 0) gbase[b] = atomicAdd(&bcur[b], hist[b]);
    __syncthreads();
    for (int i = beg + t; i < end; i += 256) {
        int d = dst[i];
        int bk = ((unsigned)d) >> 8;
        int slot = base_local[bk] + atomicAdd(&lc[bk], 1);
        le[slot] = make_int2(((d & 255) << 24) | src[i], __float_as_int(ew[i]));
        lb[slot] = (ushort)bk;
    }
    __syncthreads();
    for (int s = t; s < cnt; s += 256) {
        int bk = lb[s];
        stage[gbase[bk] + (s - base_local[bk])] = le[s];
    }
}

__global__ __launch_bounds__(256) void fine_fill_kernel(const int2* __restrict__ stage,
                                                        const int* __restrict__ rowptr,
                                                        int2* __restrict__ csr, int n) {
    __shared__ int cur[256];
    __shared__ int rp[257];
    int b = blockIdx.x, t = threadIdx.x;
    int node0 = b * 256;
    int nodes = min(256, n - node0);
    cur[t] = 0;
    rp[t] = rowptr[min(node0 + t, n)];
    if (t == 0) rp[256] = rowptr[min(node0 + 256, n)];
    __syncthreads();
    int S = rp[0], E = rp[nodes];
    for (int i = S + t; i < E; i += 256) {
        int2 en = stage[i];
        int dl = ((unsigned)en.x) >> 24;
        int pos = rp[dl] + atomicAdd(&cur[dl], 1);
        csr[pos] = make_int2(en.x & 0xFFFFFF, en.y);
    }
}

__global__ __launch_bounds__(256) void lfill_kernel(const int* __restrict__ label,
                                                    const int* __restrict__ lbase,
                                                    int* __restrict__ gcur,
                                                    int* __restrict__ perm, int n) {
    __shared__ int lh[CC], lbs[CC], lc[CC];
    int t = threadIdx.x;
    if (t < CC) lh[t] = 0;
    __syncthreads();
    int chunk = (n + gridDim.x - 1) / gridDim.x;
    int beg = blockIdx.x * chunk, end = min(n, beg + chunk);
    for (int i = beg + t; i < end; i += 256) atomicAdd(&lh[label[i]], 1);
    __syncthreads();
    if (t < CC) {
        lbs[t] = (lh[t] > 0) ? atomicAdd(&gcur[t], lh[t]) : 0;
        lc[t] = 0;
    }
    __syncthreads();
    for (int i = beg + t; i < end; i += 256) {
        int c = label[i];
        int pos = atomicAdd(&lc[c], 1);
        perm[lbase[c] + lbs[c] + pos] = (c << 24) | i;
    }
}

// ---------------- segment sums: one label per block-group (no label checks, 2 atomics/lane) ----------------
__global__ __launch_bounds__(256) void psum2_kernel(const ushort* __restrict__ xb,
                                                    const int* __restrict__ perm,
                                                    const int* __restrict__ lbase,
                                                    const int* __restrict__ lcnt,
                                                    float* __restrict__ sums) {
    int c = blockIdx.x / PPARTS;
    int part = blockIdx.x % PPARTS;
    int base = lbase[c], cnt = lcnt[c];
    int chunk = (cnt + PPARTS - 1) / PPARTS;
    int sbeg = part * chunk, send = min(cnt, sbeg + chunk);
    if (sbeg >= send) return;
    const int lane = threadIdx.x & 63;
    const int wid = threadIdx.x >> 6;
    int wlen = send - sbeg;
    int wchunk = (wlen + 3) / 4;
    int beg = base + sbeg + wid * wchunk;
    int end = min(base + send, beg + wchunk);
    if (beg >= end) return;
    float ax = 0.0f, ay = 0.0f;
    int lim = end - 1;
    #pragma unroll 1
    for (int i = beg; i < end; i += 8) {
        int pp[8];
        #pragma unroll
        for (int u = 0; u < 8; u++) {
            int idx = i + u;
            pp[u] = perm[idx < end ? idx : lim];
        }
        ushort2 vv[8];
        #pragma unroll
        for (int u = 0; u < 8; u++)
            vv[u] = *(const ushort2*)(xb + (size_t)(pp[u] & 0xFFFFFF) * HH + 2 * lane);
        #pragma unroll
        for (int u = 0; u < 8; u++) {
            bool ok = (i + u < end);
            ax += ok ? b2f(vv[u].x) : 0.0f;
            ay += ok ? b2f(vv[u].y) : 0.0f;
        }
    }
    atomicAdd(&sums[c * HH + 2 * lane], ax);
    atomicAdd(&sums[c * HH + 2 * lane + 1], ay);
}

// ---------------- lin0 (B-frags from L2); writes x0b only ----------------
__global__ __launch_bounds__(256) void lin0_mfma_kernel(const float* __restrict__ xin,
                                                        const ushort* __restrict__ Wp,
                                                        const float* __restrict__ bias,
                                                        ushort* __restrict__ x0b) {
    __shared__ ushort ts[32 * 128];
    const int lane = threadIdx.x & 63, wv = threadIdx.x >> 6;
    const int sub = lane >> 4, r16 = lane & 15;
    const int wbase = wv * 32;
    const int rowbase = blockIdx.x * 32;
    const float* tp = xin + (size_t)rowbase * HH;
    #pragma unroll
    for (int j = 0; j < 4; j++) {
        int e = 4 * threadIdx.x + j * 1024;
        float4 f = *(const float4*)(tp + e);
        int r = e >> 7, c = e & 127;
        ushort4 b4 = make_ushort4(f2bf(f.x), f2bf(f.y), f2bf(f.z), f2bf(f.w));
        int off = (r * 256 + c * 2) ^ ((r & 7) << 4);
        *(ushort4*)((char*)ts + off) = b4;
    }
    __syncthreads();
    float4v acc[2][2] = {};
    {
        const char* tsc = (const char*)ts;
        const int sw = (r16 & 7) << 4;
        #pragma unroll
        for (int ks = 0; ks < 4; ks++) {
            short8v a0 = *(const short8v*)(tsc + ((r16 * 256 + ks * 64 + sub * 16) ^ sw));
            short8v a1 = *(const short8v*)(tsc + (((16 + r16) * 256 + ks * 64 + sub * 16) ^ sw));
            int kb = (ks * 4 + sub) * 1024;
            short8v b0 = *(const short8v*)(Wp + kb + (wbase + r16) * 8);
            short8v b1 = *(const short8v*)(Wp + kb + (wbase + 16 + r16) * 8);
            acc[0][0] = __builtin_amdgcn_mfma_f32_16x16x32_bf16(a0, b0, acc[0][0], 0, 0, 0);
            acc[0][1] = __builtin_amdgcn_mfma_f32_16x16x32_bf16(a0, b1, acc[0][1], 0, 0, 0);
            acc[1][0] = __builtin_amdgcn_mfma_f32_16x16x32_bf16(a1, b0, acc[1][0], 0, 0, 0);
            acc[1][1] = __builtin_amdgcn_mfma_f32_16x16x32_bf16(a1, b1, acc[1][1], 0, 0, 0);
        }
    }
    float bv[2] = {bias[wbase + r16], bias[wbase + 16 + r16]};
    #pragma unroll
    for (int mi = 0; mi < 2; mi++)
        #pragma unroll
        for (int ni = 0; ni < 2; ni++) {
            int col = wbase + ni * 16 + r16;
            #pragma unroll
            for (int r = 0; r < 4; r++) {
                int row = rowbase + mi * 16 + sub * 4 + r;
                float v = fmaxf(acc[mi][ni][r] + bv[ni], 0.0f);
                x0b[(size_t)row * HH + col] = f2bf(v);
            }
        }
}

// ---------------- fused centers + rcm + pack ----------------
__global__ __launch_bounds__(64) void cr_kernel(const float* __restrict__ sumsx,
                                                const float* __restrict__ sums0,
                                                const float* __restrict__ cnt,
                                                const float* __restrict__ cm,
                                                ushort* __restrict__ rlp) {
    __shared__ float cs[CC * HH];
    int i = blockIdx.x, lane = threadIdx.x;
    for (int idx = lane; idx < CC * HH; idx += 64) {
        int c = idx >> 7;
        cs[idx] = (sumsx[idx] + 0.1f * sums0[idx]) / fmaxf(cnt[c], 1.0f);
    }
    __syncthreads();
    float ci0 = cs[i * HH + lane];
    float ci1 = cs[i * HH + 64 + lane];
    float acc0 = 0.0f, acc1 = 0.0f;
    for (int j = 0; j < CC; j++) {
        float d0 = ci0 - cs[j * HH + lane];
        float d1 = ci1 - cs[j * HH + 64 + lane];
        float s = d0 * d0 + d1 * d1;
        #pragma unroll
        for (int off = 32; off >= 1; off >>= 1) s += __shfl_xor(s, off);
        float nrm = sqrtf(s);
        if (nrm == 0.0f) nrm = 1.0f;
        float w = cm[i * CC + j] / nrm;
        acc0 = fmaf(w, d0, acc0);
        acc1 = fmaf(w, d1, acc1);
    }
    rlp[(i >> 3) * 1024 + lane * 8 + (i & 7)] = f2bf(acc0);
    rlp[(i >> 3) * 1024 + (lane + 64) * 8 + (i & 7)] = f2bf(acc1);
}

// ---------------- fused layer: pr MFMA (A from packed global) + gather/combine + conv MFMA ----------------
template <int FINAL>
__global__ __launch_bounds__(512, 8) void layer_kernel(
    const ushort* __restrict__ xin, const ushort* __restrict__ x0b,
    const ushort* __restrict__ pb, const ushort* __restrict__ rlp,
    const int* __restrict__ rowptr, const int2* __restrict__ csr,
    const ushort* __restrict__ Wp,
    const ushort* __restrict__ Wp1, const float* __restrict__ b1,
    ushort* __restrict__ xout, float* __restrict__ out, float beta) {
    __shared__ ushort ts[32 * 128];   // combined-t tile (swizzled)
    __shared__ ushort prs[32 * 128];  // pr result tile (swizzled)
    const int lane = threadIdx.x & 63;
    const int wv = __builtin_amdgcn_readfirstlane(threadIdx.x >> 6);
    const int rowbase = blockIdx.x * 32;
    const int sub = lane >> 4, r16 = lane & 15;
    const int sw = (r16 & 7) << 4;
    // ---- pr MFMA: A-frags direct from packed global (same addrs all waves -> broadcast) ----
    {
        const ushort* pbt = pb + (size_t)blockIdx.x * 2048;
        float4v pacc[2] = {};
        #pragma unroll
        for (int ks = 0; ks < 2; ks++) {
            int gb = (ks * 4 + sub) * 256 + r16 * 8;
            short8v a0 = *(const short8v*)(pbt + gb);
            short8v a1 = *(const short8v*)(pbt + gb + 128);
            short8v bb = *(const short8v*)(rlp + (ks * 4 + sub) * 1024 + (16 * wv + r16) * 8);
            pacc[0] = __builtin_amdgcn_mfma_f32_16x16x32_bf16(a0, bb, pacc[0], 0, 0, 0);
            pacc[1] = __builtin_amdgcn_mfma_f32_16x16x32_bf16(a1, bb, pacc[1], 0, 0, 0);
        }
        int col = 16 * wv + r16;
        #pragma unroll
        for (int mi = 0; mi < 2; mi++)
            #pragma unroll
            for (int r = 0; r < 4; r++) {
                int rl_ = mi * 16 + sub * 4 + r;
                *(ushort*)((char*)prs + ((rl_ * 256 + col * 2) ^ ((rl_ & 7) << 4))) =
                    f2bf(pacc[mi][r]);
            }
    }
    __syncthreads();
    // ---- gather + combine -> ts (clamped full batches: one wait per 8 edges) ----
    const int nn0 = rowbase + 4 * wv;
    int rp0 = __builtin_amdgcn_readfirstlane(rowptr[nn0]);
    int rp1 = __builtin_amdgcn_readfirstlane(rowptr[nn0 + 1]);
    int rp2 = __builtin_amdgcn_readfirstlane(rowptr[nn0 + 2]);
    int rp3 = __builtin_amdgcn_readfirstlane(rowptr[nn0 + 3]);
    int rp4 = __builtin_amdgcn_readfirstlane(rowptr[nn0 + 4]);
    int rps[5] = {rp0, rp1, rp2, rp3, rp4};
    #pragma unroll 1
    for (int k = 0; k < 4; k++) {
        int rloc = 4 * wv + k;
        int nn = nn0 + k;
        int beg = rps[k], end = rps[k + 1];
        // issue residual loads early (independent of edge loop)
        ushort2 xc = *(const ushort2*)(xin + (size_t)nn * HH + 2 * lane);
        ushort2 xo = *(const ushort2*)(x0b + (size_t)nn * HH + 2 * lane);
        float accx = 0.0f, accy = 0.0f;
        int lim = end - 1;
        #pragma unroll 1
        for (int e2 = beg; e2 < end; e2 += 8) {
            int2 ed[8];
            #pragma unroll
            for (int u = 0; u < 8; u++) {
                int idx = e2 + u;
                ed[u] = csr[idx < end ? idx : lim];
            }
            ushort2 vv[8];
            #pragma unroll
            for (int u = 0; u < 8; u++)
                vv[u] = *(const ushort2*)(xin + (size_t)ed[u].x * HH + 2 * lane);
            #pragma unroll
            for (int u = 0; u < 8; u++) {
                float w = (e2 + u < end) ? __int_as_float(ed[u].y) : 0.0f;
                accx = fmaf(w, b2f(vv[u].x), accx);
                accy = fmaf(w, b2f(vv[u].y), accy);
            }
        }
        int poff = (rloc * 256 + lane * 4) ^ ((rloc & 7) << 4);
        ushort2 pv = *(const ushort2*)((const char*)prs + poff);
        ushort2 o;
        o.x = f2bf(0.45f * b2f(xc.x) + 0.45f * b2f(pv.x) + 0.45f * accx + 0.1f * b2f(xo.x));
        o.y = f2bf(0.45f * b2f(xc.y) + 0.45f * b2f(pv.y) + 0.45f * accy + 0.1f * b2f(xo.y));
        *(ushort2*)((char*)ts + poff) = o;
    }
    __syncthreads();
    // ---- conv MFMA: wave wv owns cols [16wv,16wv+16); B-frags from L2 ----
    const char* tsc = (const char*)ts;
    float4v acc[2] = {};
    #pragma unroll
    for (int ks = 0; ks < 4; ks++) {
        short8v a0 = *(const short8v*)(tsc + ((r16 * 256 + ks * 64 + sub * 16) ^ sw));
        short8v a1 = *(const short8v*)(tsc + (((16 + r16) * 256 + ks * 64 + sub * 16) ^ sw));
        short8v bb = *(const short8v*)(Wp + (ks * 4 + sub) * 1024 + (16 * wv + r16) * 8);
        acc[0] = __builtin_amdgcn_mfma_f32_16x16x32_bf16(a0, bb, acc[0], 0, 0, 0);
        acc[1] = __builtin_amdgcn_mfma_f32_16x16x32_bf16(a1, bb, acc[1], 0, 0, 0);
    }
    const float omb = 1.0f - beta;
    const int col = 16 * wv + r16;
    if constexpr (!FINAL) {
        #pragma unroll
        for (int mi = 0; mi < 2; mi++)
            #pragma unroll
            for (int r = 0; r < 4; r++) {
                int rl_ = mi * 16 + sub * 4 + r;
                int toff = (rl_ * 256 + col * 2) ^ ((rl_ & 7) << 4);
                float tv = b2f(*(const ushort*)(tsc + toff));
                float v = fmaxf(omb * tv + beta * acc[mi][r], 0.0f);
                xout[(size_t)(rowbase + rl_) * HH + col] = f2bf(v);
            }
    } else {
        __syncthreads();
        #pragma unroll
        for (int mi = 0; mi < 2; mi++)
            #pragma unroll
            for (int r = 0; r < 4; r++) {
                int rl_ = mi * 16 + sub * 4 + r;
                int toff = (rl_ * 256 + col * 2) ^ ((rl_ & 7) << 4);
                ushort* slot = (ushort*)((char*)ts + toff);
                float tv = b2f(*slot);
                float v = fmaxf(omb * tv + beta * acc[mi][r], 0.0f);
                *slot = f2bf(v);
            }
        __syncthreads();
        if (wv < 3) {
            float4v a2[2] = {};
            #pragma unroll
            for (int ks = 0; ks < 4; ks++) {
                short8v a0 = *(const short8v*)(tsc + ((r16 * 256 + ks * 64 + sub * 16) ^ sw));
                short8v a1 = *(const short8v*)(tsc + (((16 + r16) * 256 + ks * 64 + sub * 16) ^ sw));
                short8v bb = *(const short8v*)(Wp1 + (ks * 4 + sub) * 384 + (wv * 16 + r16) * 8);
                a2[0] = __builtin_amdgcn_mfma_f32_16x16x32_bf16(a0, bb, a2[0], 0, 0, 0);
                a2[1] = __builtin_amdgcn_mfma_f32_16x16x32_bf16(a1, bb, a2[1], 0, 0, 0);
            }
            int col2 = wv * 16 + r16;
            if (col2 < CC) {
                float bias = b1[col2];
                #pragma unroll
                for (int mi = 0; mi < 2; mi++)
                    #pragma unroll
                    for (int r = 0; r < 4; r++) {
                        int row = rowbase + mi * 16 + sub * 4 + r;
                        out[(size_t)row * CC + col2] = a2[mi][r] + bias;
                    }
            }
        }
    }
}

extern "C" void kernel_launch(void* const* d_in, const int* in_sizes, int n_in,
                              void* d_out, int out_size, void* d_ws, size_t ws_size,
                              hipStream_t stream) {
    const float* x_in   = (const float*)d_in[0];
    const int*   ei     = (const int*)d_in[1];
    const float* ew     = (const float*)d_in[2];
    const int*   label  = (const int*)d_in[3];
    const float* p      = (const float*)d_in[4];
    const float* cm     = (const float*)d_in[5];
    const float* lin0_w = (const float*)d_in[6];
    const float* lin0_b = (const float*)d_in[7];
    const float* lin1_w = (const float*)d_in[8];
    const float* lin1_b = (const float*)d_in[9];
    const float* conv_w = (const float*)d_in[10];
    float* out = (float*)d_out;

    const int* src = ei;
    const int* dst = ei + EE;

    const size_t NH = (size_t)NN * HH;
    float* ws = (float*)d_ws;
    // ---- zero zone (contiguous): sums0, sumsxs[3], rlp, deg, lcnt ----
    float* sums0  = ws;                        // CH
    float* sumsxs = sums0 + CH;                // 3*CH
    ushort* rlp   = (ushort*)(sumsxs + 3 * CH);// 8192 ushorts = 4096 f32
    int*   deg    = (int*)(rlp + 8192);        // NN
    int*   lcnt   = deg + NN;                  // 64
    const int ZTOT = CH + 3 * CH + 4096 + NN + 64;
    // ---- rest ----
    float* cnt    = (float*)(lcnt + 64);       // 64
    int*   rowptr = (int*)(cnt + 64);          // NN+1 (+pad)
    int*   bsum   = rowptr + NN + 64;          // 256
    int*   bcur   = bsum + 256;                // 512
    int*   lbase  = bcur + 512;                // 64
    int*   gcur   = lbase + 64;                // 64
    int*   perm   = gcur + 64;                 // NN
    int2*  csr    = (int2*)(perm + NN);        // EE
    int2*  stage  = csr + EE;                  // EE
    ushort* x0b   = (ushort*)(stage + EE);     // NH bf16
    ushort* xbA   = x0b + NH;                  // NH bf16
    ushort* xbB   = xbA + NH;                  // NH bf16
    ushort* wp0   = xbB + NH;                  // 16384
    ushort* wpc   = wp0 + 16384;               // 4*16384
    ushort* wp1   = wpc + 4 * 16384;           // 6144 (pad to 8192)
    ushort* pb    = wp1 + 8192;                // PBN (12.8 MB)

    // ---- prep: zero + pack weights + pack p (one launch) ----
    prep_kernel<<<512, 256, 0, stream>>>(lin0_w, conv_w, lin1_w, p, wp0, wpc, wp1, pb,
                                         (int*)ws, ZTOT);

    // ---- CSR + label-sort build ----
    hist2_kernel<<<(EE + 255) / 256, 256, 0, stream>>>(dst, deg, label, lcnt, EE, NN);
    const int NBLK = (NN + 511) / 512;
    scan_block_kernel<<<NBLK, 256, 0, stream>>>(deg, rowptr, bsum, NN);
    scan2_kernel<<<2, 256, 0, stream>>>(bsum, NBLK, lcnt, lbase, gcur, cnt);
    addoff_init_kernel<<<(NN + 255) / 256, 256, 0, stream>>>(rowptr, bsum, bcur, NN);
    coarse_fill_kernel<<<(EE + CHUNK - 1) / CHUNK, 256, 0, stream>>>(src, dst, ew, bcur, stage, EE);
    fine_fill_kernel<<<NB, 256, 0, stream>>>(stage, rowptr, csr, NN);
    lfill_kernel<<<256, 256, 0, stream>>>(label, lbase, gcur, perm, NN);

    // input linear + relu (writes x0b only; layer 0 reads it as xin)
    lin0_mfma_kernel<<<NN / 32, 256, 0, stream>>>(x_in, wp0, lin0_b, x0b);

    // sums0 = sum_label x0
    psum2_kernel<<<CC * PPARTS, 256, 0, stream>>>(x0b, perm, lbase, lcnt, sums0);

    const float betas[4] = {logf(0.5f / 1.0f + 1.0f), logf(0.5f / 2.0f + 1.0f),
                            logf(0.5f / 3.0f + 1.0f), logf(0.5f / 4.0f + 1.0f)};

    ushort* xin_b = x0b;   // layer 0 input = x0
    ushort* xout_b = xbA;
    for (int i = 0; i < 4; i++) {
        if (i == 0) {
            cr_kernel<<<CC, 64, 0, stream>>>(sums0, sums0, cnt, cm, rlp);
        } else {
            float* sx = sumsxs + (size_t)(i - 1) * CH;
            psum2_kernel<<<CC * PPARTS, 256, 0, stream>>>(xin_b, perm, lbase, lcnt, sx);
            cr_kernel<<<CC, 64, 0, stream>>>(sx, sums0, cnt, cm, rlp);
        }
        if (i < 3) {
            layer_kernel<0><<<NN / 32, 512, 0, stream>>>(xin_b, x0b, pb, rlp, rowptr, csr,
                                                         wpc + (size_t)i * 16384, wp1, lin1_b,
                                                         xout_b, out, betas[i]);
            // cycle buffers: next input is this output; next output alternates xbA/xbB
            xin_b = xout_b;
            xout_b = (xout_b == xbA) ? xbB : xbA;
        } else {
            layer_kernel<1><<<NN / 32, 512, 0, stream>>>(xin_b, x0b, pb, rlp, rowptr, csr,
                                                         wpc + 3 * 16384, wp1, lin1_b,
                                                         xout_b, out, betas[3]);
        }
    }
}